// Round 1
// baseline (2719.050 us; speedup 1.0000x reference)
//
#include <hip/hip_runtime.h>
#include <math.h>

// Problem constants (match reference)
#define IN_DIM 8
#define MID    128
#define HALFC  4
#define NB     8
#define BATCH  32
#define HWPIX  9216                 // 96*96
#define NPIX   (BATCH * HWPIX)      // 294912

// Channel patterns: pairs = [(a1,a2),(a2,a1),(b1,b2),(b2,b1)] * 2
// ci = pair[0] (changed), fi = pair[1] (fixed / MLP input)
__device__ __constant__ int d_dummy; // (unused; keep TU non-trivial)

__global__ __launch_bounds__(256, 2)
void realnvp_fused_fp32(const float* __restrict__ x_in,
                        const float* __restrict__ W1, const float* __restrict__ b1,
                        const float* __restrict__ W2, const float* __restrict__ b2,
                        const float* __restrict__ W3, const float* __restrict__ b3,
                        float* __restrict__ out)
{
    // grid exactly covers NPIX -> no divergent guard (keeps weight loads
    // provably uniform -> s_load scalarization)
    const int p   = blockIdx.x * blockDim.x + threadIdx.x;
    const int b   = p / HWPIX;
    const int rem = p - b * HWPIX;

    const float* xb = x_in + (size_t)b * IN_DIM * HWPIX + rem;

    float xc[IN_DIM];
#pragma unroll
    for (int c = 0; c < IN_DIM; ++c) xc[c] = xb[(size_t)c * HWPIX];

    float logdet = 0.f;

    constexpr int CI[4][4] = {{0,1,2,3},{4,5,6,7},{0,2,4,6},{1,3,5,7}};
    constexpr int FI[4][4] = {{4,5,6,7},{0,1,2,3},{1,3,5,7},{0,2,4,6}};

#pragma unroll
    for (int i = 0; i < NB; ++i) {
        const int pat = i & 3;

        float xf[HALFC];
#pragma unroll
        for (int k = 0; k < HALFC; ++k) xf[k] = xc[FI[pat][k]];

        // ---- L1: h1 = leaky_relu(W1 @ x_fix + b1), fully unrolled ----
        const float* w1  = W1 + i * MID * HALFC;
        const float* bb1 = b1 + i * MID;
        float h1[MID];
#pragma unroll
        for (int o = 0; o < MID; ++o) {
            float a = bb1[o];
            a = fmaf(w1[o*4+0], xf[0], a);
            a = fmaf(w1[o*4+1], xf[1], a);
            a = fmaf(w1[o*4+2], xf[2], a);
            a = fmaf(w1[o*4+3], xf[3], a);
            h1[o] = a > 0.f ? a : 0.01f * a;
        }

        // ---- L2 + L3 fused: never materialize h2 ----
        const float* w2  = W2 + i * MID * MID;
        const float* bb2 = b2 + i * MID;
        const float* w3  = W3 + i * (2*HALFC) * MID;
        const float* bb3 = b3 + i * (2*HALFC);

        float st[2*HALFC];
#pragma unroll
        for (int o2 = 0; o2 < 2*HALFC; ++o2) st[o2] = bb3[o2];

        for (int o = 0; o < MID; ++o) {            // runtime loop (uniform)
            const float* row = w2 + o * MID;
            float a0 = 0.f, a1 = 0.f, a2 = 0.f, a3 = 0.f;
#pragma unroll
            for (int c = 0; c < MID; c += 4) {
                a0 = fmaf(row[c+0], h1[c+0], a0);
                a1 = fmaf(row[c+1], h1[c+1], a1);
                a2 = fmaf(row[c+2], h1[c+2], a2);
                a3 = fmaf(row[c+3], h1[c+3], a3);
            }
            float hv = (a0 + a1) + (a2 + a3) + bb2[o];
            float r  = hv > 0.f ? hv : 0.01f * hv;   // leaky_relu(h2)
#pragma unroll
            for (int o2 = 0; o2 < 2*HALFC; ++o2)
                st[o2] = fmaf(w3[o2*MID + o], r, st[o2]);
        }

        // ---- affine coupling update ----
#pragma unroll
        for (int k = 0; k < HALFC; ++k) {
            float s = tanhf(st[k]);
            float t = tanhf(st[k + HALFC]);
            const int c = CI[pat][k];
            xc[c] = xc[c] * expf(s) + t;
            logdet += s;
        }
    }

    // ---- write outputs: x (B,8,H,W) then log_det (B,1,H,W) ----
    float* outx = out + (size_t)b * IN_DIM * HWPIX + rem;
#pragma unroll
    for (int c = 0; c < IN_DIM; ++c) outx[(size_t)c * HWPIX] = xc[c];
    out[(size_t)NPIX * IN_DIM + (size_t)b * HWPIX + rem] = logdet;
}

extern "C" void kernel_launch(void* const* d_in, const int* in_sizes, int n_in,
                              void* d_out, int out_size, void* d_ws, size_t ws_size,
                              hipStream_t stream)
{
    const float* x  = (const float*)d_in[0];
    const float* W1 = (const float*)d_in[1];
    const float* b1 = (const float*)d_in[2];
    const float* W2 = (const float*)d_in[3];
    const float* b2 = (const float*)d_in[4];
    const float* W3 = (const float*)d_in[5];
    const float* b3 = (const float*)d_in[6];
    float* out = (float*)d_out;

    const int threads = 256;
    const int blocks  = NPIX / threads;   // 294912 / 256 = 1152 exactly

    hipLaunchKernelGGL(realnvp_fused_fp32, dim3(blocks), dim3(threads), 0, stream,
                       x, W1, b1, W2, b2, W3, b3, out);
}

// Round 3
// 240.648 us; speedup vs baseline: 11.2989x; 11.2989x over previous
//
#include <hip/hip_runtime.h>
#include <math.h>
#include <stdint.h>

// RealNVP fused, MFMA version.
// Design: every pointwise layer is computed "swapped": A-operand = weights
// (rows = output channels), B-operand = activations (cols = pixels).
// With v_mfma_f32_16x16x16_f16, D layout (col=lane&15,row=4g+r) == B k-layout
// (col=lane&15,k=4g+e), so layers chain in-register (no transpose, no LDS
// round-trip for activations). Biases = extra rank-1 K-chunk with const-1 B.
// Weights are pre-converted to f16 A-fragment layout in d_ws (prep kernel),
// staged to LDS per stage. Wave owns 32 pixels (2 column tiles); x state fp32.

#define HWPIX   9216
#define NPIX    294912
#define WSTRIDE 53248          // bytes per stage in ws (13 * 4096, 49 pair-slots used)
#define NFRAG   89             // 8 (L1) + 72 (L2: 8m x 9kc) + 9 (L3)

typedef float    f32x4 __attribute__((ext_vector_type(4)));
typedef _Float16 f16x4 __attribute__((ext_vector_type(4)));
typedef _Float16 f16x8 __attribute__((ext_vector_type(8)));
typedef uint32_t u32x4 __attribute__((ext_vector_type(4)));

// ---------------------------------------------------------------------------
// prep: build f16 A-fragments (and bias slots) in ws.
// frag f: 0..7 = L1 m; 8..79 = L2 (m=(f-8)/9, kc=(f-8)%9); 80..88 = L3 kc.
// pair-slot layout: [pair][lane][16B] = frag_even(8B) | frag_odd(8B)
//   L1: pair = f>>1, half=f&1
//   L2: pair = 4 + m*5 + (kc>>1), half=kc&1
//   L3: pair = 44 + (kc>>1),      half=kc&1
// ---------------------------------------------------------------------------
__global__ __launch_bounds__(256)
void prep_frags(const float* __restrict__ W1, const float* __restrict__ b1,
                const float* __restrict__ W2, const float* __restrict__ b2,
                const float* __restrict__ W3, const float* __restrict__ b3,
                _Float16* __restrict__ ws)
{
    int t = blockIdx.x * 256 + threadIdx.x;   // 8*89*64 = 45568 threads exactly
    if (t >= 8 * NFRAG * 64) return;
    const int lane  = t & 63;
    const int f     = (t >> 6) % NFRAG;
    const int stage = t / (NFRAG * 64);
    const int pl = lane & 15, g = lane >> 4;
    const int pat = stage & 3;

    float v[4];
#pragma unroll
    for (int e = 0; e < 4; ++e) {
        const int k = 4 * g + e;       // K-slot within 16-wide chunk
        float val = 0.f;
        if (f < 8) {                   // L1: W1 padded to k=channel, +b1 at k=8
            const int o = 16 * f + pl;
            if (k < 8) {
                int j = -1;
                if      (pat == 0) j = (k >= 4) ? (k - 4) : -1;  // fi={4,5,6,7}
                else if (pat == 1) j = (k < 4)  ? k        : -1; // fi={0,1,2,3}
                else if (pat == 2) j = (k & 1)  ? (k >> 1) : -1; // fi={1,3,5,7}
                else               j = (k & 1)  ? -1 : (k >> 1); // fi={0,2,4,6}
                if (j >= 0) val = W1[stage * 512 + o * 4 + j];
            } else if (k == 8) {
                val = b1[stage * 128 + o];
            }
        } else if (f < 80) {           // L2: W2[o][16kc+k], kc=8 -> b2 at k=0
            const int idx = f - 8, m = idx / 9, kc = idx % 9;
            const int o = 16 * m + pl;
            if (kc < 8)      val = W2[stage * 16384 + o * 128 + 16 * kc + k];
            else if (k == 0) val = b2[stage * 128 + o];
        } else {                       // L3: rows 8..15 zero-padded, kc=8 -> b3
            const int kc = f - 80;
            const int o3 = pl;
            if (o3 < 8) {
                if (kc < 8)      val = W3[stage * 1024 + o3 * 128 + 16 * kc + k];
                else if (k == 0) val = b3[stage * 8 + o3];
            }
        }
        v[e] = val;
    }

    int pair, half;
    if (f < 8)       { pair = f >> 1;                          half = f & 1; }
    else if (f < 80) { const int idx = f - 8;
                       pair = 4 + (idx / 9) * 5 + ((idx % 9) >> 1);
                       half = (idx % 9) & 1; }
    else             { const int kc = f - 80;
                       pair = 44 + (kc >> 1);                  half = kc & 1; }

    _Float16* dst = ws + (stage * WSTRIDE + pair * 1024 + lane * 16 + half * 8) / 2;
    dst[0] = (_Float16)v[0]; dst[1] = (_Float16)v[1];
    dst[2] = (_Float16)v[2]; dst[3] = (_Float16)v[3];
}

// ---------------------------------------------------------------------------
// main kernel
// ---------------------------------------------------------------------------
__device__ __forceinline__ void load_pair(const void* p, f16x4& a, f16x4& b) {
    f16x8 v = *(const f16x8*)p;                        // ds_read_b128
    a = __builtin_shufflevector(v, v, 0, 1, 2, 3);
    b = __builtin_shufflevector(v, v, 4, 5, 6, 7);
}

__global__ __launch_bounds__(256, 3)
void realnvp_mfma(const float* __restrict__ x_in,
                  const _Float16* __restrict__ wfrag,
                  float* __restrict__ out)
{
    __shared__ __align__(16) _Float16 lds[WSTRIDE / 2];   // 52 KiB -> 3 blocks/CU

    const int tid  = threadIdx.x;
    const int w    = tid >> 6;
    const int lane = tid & 63;
    const int pl = lane & 15, g = lane >> 4;

    const int blockpx = blockIdx.x * 128;          // 128 px per block (4 waves x 32)
    const int bb   = blockpx / HWPIX;              // batch (9216 % 128 == 0)
    const int rem0 = blockpx - bb * HWPIX + w * 32;
    const float* xb = x_in + (size_t)bb * 8 * HWPIX + rem0;

    // persistent per-lane state: 4 channels (ch = 4g+e, valid g<2) x 2 tiles
    float xv[2][4];
    float logdet[2] = {0.f, 0.f};
#pragma unroll
    for (int t = 0; t < 2; ++t)
#pragma unroll
        for (int e = 0; e < 4; ++e)
            xv[t][e] = (g < 2) ? xb[(size_t)(4 * g + e) * HWPIX + t * 16 + pl] : 0.f;

    // constant bias-slot B operand: 1 at k_local==0 (g==0, e==0)
    f16x4 cone = {(_Float16)0.f, (_Float16)0.f, (_Float16)0.f, (_Float16)0.f};
    if (g == 0) cone[0] = (_Float16)1.f;

#pragma unroll 1
    for (int st = 0; st < 8; ++st) {
        __syncthreads();                            // prior-stage LDS reads done
        // stage weights -> LDS (reg-staged copy: 13 x 4 KiB)
        {
            const char* gsrc = (const char*)wfrag + st * WSTRIDE + tid * 16;
            char*       ldst = (char*)lds + tid * 16;
#pragma unroll
            for (int it = 0; it < 13; ++it)
                *(u32x4*)(ldst + it * 4096) = *(const u32x4*)(gsrc + it * 4096);
        }
        __syncthreads();

        // x B-fragments (f16), bias-one at k=8 -> lane g==2, e==0
        f16x4 xh[2];
#pragma unroll
        for (int t = 0; t < 2; ++t) {
            f16x4 h;
#pragma unroll
            for (int e = 0; e < 4; ++e) h[e] = (_Float16)xv[t][e];
            if (g == 2) h[0] = (_Float16)1.f;
            xh[t] = h;
        }

        // ---- L1: h1 = leaky(W1pad @ [x;1]) ----
        f16x4 h1[2][8];
        {
            f16x4 w1f[8];
#pragma unroll
            for (int pr = 0; pr < 4; ++pr)
                load_pair((const char*)lds + pr * 1024 + lane * 16,
                          w1f[2 * pr], w1f[2 * pr + 1]);
#pragma unroll
            for (int m = 0; m < 8; ++m)
#pragma unroll
                for (int t = 0; t < 2; ++t) {
                    f32x4 acc = {0.f, 0.f, 0.f, 0.f};
                    acc = __builtin_amdgcn_mfma_f32_16x16x16f16(w1f[m], xh[t], acc, 0, 0, 0);
                    f16x4 h;
#pragma unroll
                    for (int r = 0; r < 4; ++r) {
                        float a = acc[r];
                        a = a > 0.f ? a : 0.01f * a;
                        h[r] = (_Float16)a;
                    }
                    h1[t][m] = h;
                }
        }

        // ---- L2: h2 = leaky(W2 @ h1 + b2) ----
        f16x4 h2[2][8];
#pragma unroll
        for (int m = 0; m < 8; ++m) {
            const char* base = (const char*)lds + (4 + m * 5) * 1024 + lane * 16;
            f16x4 wf[9];
#pragma unroll
            for (int pr = 0; pr < 4; ++pr)
                load_pair(base + pr * 1024, wf[2 * pr], wf[2 * pr + 1]);
            wf[8] = *(const f16x4*)(base + 4 * 1024);
#pragma unroll
            for (int t = 0; t < 2; ++t) {
                f32x4 acc = {0.f, 0.f, 0.f, 0.f};
#pragma unroll
                for (int kc = 0; kc < 8; ++kc)
                    acc = __builtin_amdgcn_mfma_f32_16x16x16f16(wf[kc], h1[t][kc], acc, 0, 0, 0);
                acc = __builtin_amdgcn_mfma_f32_16x16x16f16(wf[8], cone, acc, 0, 0, 0);
                f16x4 h;
#pragma unroll
                for (int r = 0; r < 4; ++r) {
                    float a = acc[r];
                    a = a > 0.f ? a : 0.01f * a;
                    h[r] = (_Float16)a;
                }
                h2[t][m] = h;
            }
        }

        // ---- L3 + coupling ----
        {
            const char* base = (const char*)lds + 44 * 1024 + lane * 16;
            f16x4 wf[9];
#pragma unroll
            for (int pr = 0; pr < 4; ++pr)
                load_pair(base + pr * 1024, wf[2 * pr], wf[2 * pr + 1]);
            wf[8] = *(const f16x4*)(base + 4 * 1024);

            const int pat = st & 3;
#pragma unroll
            for (int t = 0; t < 2; ++t) {
                f32x4 acc = {0.f, 0.f, 0.f, 0.f};
#pragma unroll
                for (int kc = 0; kc < 8; ++kc)
                    acc = __builtin_amdgcn_mfma_f32_16x16x16f16(wf[kc], h2[t][kc], acc, 0, 0, 0);
                acc = __builtin_amdgcn_mfma_f32_16x16x16f16(wf[8], cone, acc, 0, 0, 0);

                // D rows: g0 -> st[0..3] (s-pre), g1 -> st[4..7] (t-pre)
                float sv[4], ov[4];
#pragma unroll
                for (int r = 0; r < 4; ++r) sv[r] = tanhf(acc[r]);
#pragma unroll
                for (int r = 0; r < 4; ++r)
                    ov[r] = __int_as_float(
                        __builtin_amdgcn_ds_swizzle(__float_as_int(sv[r]), 0x401F)); // lane ^= 16

                if (g == 0) logdet[t] += sv[0] + sv[1] + sv[2] + sv[3];

                // g0 lanes: local=s, other=t ; g1 lanes: local=t, other=s
                float xn[4];
#pragma unroll
                for (int e = 0; e < 4; ++e) xn[e] = xv[t][e];
                if (pat == 0) {            // ci={0,1,2,3} @ g0, k=e
#pragma unroll
                    for (int e = 0; e < 4; ++e)
                        if (g == 0) xn[e] = xv[t][e] * expf(sv[e]) + ov[e];
                } else if (pat == 1) {     // ci={4,5,6,7} @ g1, k=e
#pragma unroll
                    for (int e = 0; e < 4; ++e)
                        if (g == 1) xn[e] = xv[t][e] * expf(ov[e]) + sv[e];
                } else if (pat == 2) {     // ci={0,2,4,6}: even e
#pragma unroll
                    for (int e = 0; e < 4; e += 2) {
                        const int k0 = e >> 1, k1 = 2 + (e >> 1);
                        if (g == 0) xn[e] = xv[t][e] * expf(sv[k0]) + ov[k0];
                        if (g == 1) xn[e] = xv[t][e] * expf(ov[k1]) + sv[k1];
                    }
                } else {                   // ci={1,3,5,7}: odd e
#pragma unroll
                    for (int e = 1; e < 4; e += 2) {
                        const int k0 = e >> 1, k1 = 2 + (e >> 1);
                        if (g == 0) xn[e] = xv[t][e] * expf(sv[k0]) + ov[k0];
                        if (g == 1) xn[e] = xv[t][e] * expf(ov[k1]) + sv[k1];
                    }
                }
#pragma unroll
                for (int e = 0; e < 4; ++e) xv[t][e] = xn[e];
            }
        }
    }

    // ---- outputs: x (B,8,H,W) then log_det (B,1,H,W) ----
    float* outx = out + (size_t)bb * 8 * HWPIX + rem0;
#pragma unroll
    for (int t = 0; t < 2; ++t) {
        if (g < 2)
#pragma unroll
            for (int e = 0; e < 4; ++e)
                outx[(size_t)(4 * g + e) * HWPIX + t * 16 + pl] = xv[t][e];
        if (g == 0)
            out[(size_t)NPIX * 8 + (size_t)bb * HWPIX + rem0 + t * 16 + pl] = logdet[t];
    }
}

extern "C" void kernel_launch(void* const* d_in, const int* in_sizes, int n_in,
                              void* d_out, int out_size, void* d_ws, size_t ws_size,
                              hipStream_t stream)
{
    const float* x  = (const float*)d_in[0];
    const float* W1 = (const float*)d_in[1];
    const float* b1 = (const float*)d_in[2];
    const float* W2 = (const float*)d_in[3];
    const float* b2 = (const float*)d_in[4];
    const float* W3 = (const float*)d_in[5];
    const float* b3 = (const float*)d_in[6];
    float* out = (float*)d_out;
    _Float16* ws = (_Float16*)d_ws;

    hipLaunchKernelGGL(prep_frags, dim3(178), dim3(256), 0, stream,
                       W1, b1, W2, b2, W3, b3, ws);
    hipLaunchKernelGGL(realnvp_mfma, dim3(NPIX / 128), dim3(256), 0, stream,
                       x, ws, out);
}

// Round 5
// 175.646 us; speedup vs baseline: 15.4803x; 1.3701x over previous
//
#include <hip/hip_runtime.h>
#include <math.h>
#include <stdint.h>

// RealNVP fused, MFMA v2 (compile-fixed: cvt_pkrtz returns __fp16x2).
// - L2/L3 use v_mfma_f32_16x16x32_f16 (gfx950 2xK). Assumed A/B layout:
//   regs 0-1 = K=16 block0 (k=4g+e), regs 2-3 = K=16 block1 (k=16+4g+e).
//   Under this, next-layer B operand = concat of two adjacent D fragments
//   (zero cross-lane chaining, same as the K=16 scheme).
// - Biases enter as the MFMA C-initializer (no bias MFMA chunks, no cone).
// - VALU diet: fast tanh via v_exp+v_rcp, __expf, v_cvt_pkrtz + packed f16
//   mul/max for leaky+cvt.
// LDS layout per stage (WSTRIDE=45056 B = 11*4096):
//   [0,4096)      L1 K=16 A-frag pairs: pair p: frag(2p)|frag(2p+1), lane*16
//   [4096,36864)  L2 K=32 A-frags: (m*4+c)*1024 + lane*16
//   [36864,40960) L3 K=32 A-frags: c*1024 + lane*16 (rows 8..15 zero)
//   [40960,41472) b1 f32[128]; [41472,41984) b2 f32[128]; [41984,42048) b3 f32[16]
//   [42048,45056) pad (staged, unused)

#define HWPIX   9216
#define NPIX    294912
#define WSTRIDE 45056
#define NFRAG   45
#define L2OFF   4096
#define L3OFF   36864
#define B1OFF   40960
#define B2OFF   41472
#define B3OFF   41984

typedef float    f32x4 __attribute__((ext_vector_type(4)));
typedef _Float16 f16x4 __attribute__((ext_vector_type(4)));
typedef _Float16 f16x8 __attribute__((ext_vector_type(8)));
typedef uint32_t u32x4 __attribute__((ext_vector_type(4)));

// ---------------------------------------------------------------------------
__global__ __launch_bounds__(256)
void prep_frags(const float* __restrict__ W1, const float* __restrict__ b1,
                const float* __restrict__ W2, const float* __restrict__ b2,
                const float* __restrict__ W3, const float* __restrict__ b3,
                char* __restrict__ ws)
{
    int t = blockIdx.x * 256 + threadIdx.x;      // 8*45*64 = 23040 exactly
    if (t >= 8 * NFRAG * 64) return;
    const int lane  = t & 63;
    const int f     = (t >> 6) % NFRAG;
    const int stage = t / (NFRAG * 64);
    const int pl = lane & 15, g = lane >> 4;
    const int pat = stage & 3;
    char* base = ws + stage * WSTRIDE;

    if (f < 8) {                       // L1 K=16 frag m=f (x-channel k, fi-folded)
        const int m = f;
        _Float16* dst = (_Float16*)(base + (m >> 1) * 1024 + lane * 16 + (m & 1) * 8);
#pragma unroll
        for (int e = 0; e < 4; ++e) {
            const int k = 4 * g + e;
            float val = 0.f;
            if (k < 8) {
                int j = -1;
                if      (pat == 0) j = (k >= 4) ? (k - 4) : -1;  // fi={4,5,6,7}
                else if (pat == 1) j = (k < 4)  ? k        : -1; // fi={0,1,2,3}
                else if (pat == 2) j = (k & 1)  ? (k >> 1) : -1; // fi={1,3,5,7}
                else               j = (k & 1)  ? -1 : (k >> 1); // fi={0,2,4,6}
                if (j >= 0) val = W1[stage * 512 + (16 * m + pl) * 4 + j];
            }
            dst[e] = (_Float16)val;
        }
    } else if (f < 40) {               // L2 K=32 frag (m,c)
        const int idx = f - 8, m = idx >> 2, c = idx & 3;
        _Float16* dst = (_Float16*)(base + L2OFF + idx * 1024 + lane * 16);
#pragma unroll
        for (int e = 0; e < 8; ++e) {
            const int k32 = (e < 4) ? (4 * g + e) : (16 + 4 * g + (e - 4));
            dst[e] = (_Float16)W2[stage * 16384 + (16 * m + pl) * 128 + 32 * c + k32];
        }
    } else if (f < 44) {               // L3 K=32 frag c (rows 8..15 zero)
        const int c = f - 40;
        _Float16* dst = (_Float16*)(base + L3OFF + c * 1024 + lane * 16);
#pragma unroll
        for (int e = 0; e < 8; ++e) {
            const int k32 = (e < 4) ? (4 * g + e) : (16 + 4 * g + (e - 4));
            dst[e] = (pl < 8) ? (_Float16)W3[stage * 1024 + pl * 128 + 32 * c + k32]
                              : (_Float16)0.f;
        }
    } else {                           // biases (f32)
        float* d1 = (float*)(base + B1OFF);
        d1[2 * lane]     = b1[stage * 128 + 2 * lane];
        d1[2 * lane + 1] = b1[stage * 128 + 2 * lane + 1];
        float* d2 = (float*)(base + B2OFF);
        d2[2 * lane]     = b2[stage * 128 + 2 * lane];
        d2[2 * lane + 1] = b2[stage * 128 + 2 * lane + 1];
        if (lane < 16)
            ((float*)(base + B3OFF))[lane] = (lane < 8) ? b3[stage * 8 + lane] : 0.f;
    }
}

// ---------------------------------------------------------------------------
__device__ __forceinline__ void load_pair(const void* p, f16x4& a, f16x4& b) {
    f16x8 v = *(const f16x8*)p;                        // ds_read_b128
    a = __builtin_shufflevector(v, v, 0, 1, 2, 3);
    b = __builtin_shufflevector(v, v, 4, 5, 6, 7);
}

__device__ __forceinline__ f16x8 cat8(f16x4 a, f16x4 b) {
    return __builtin_shufflevector(a, b, 0, 1, 2, 3, 4, 5, 6, 7);
}

// pack two f32 -> f16x2-as-_Float16 pair (cvt_pkrtz returns __fp16 vec -> convert)
__device__ __forceinline__ f16x4 pack4(float a0, float a1, float a2, float a3) {
    auto lo = __builtin_amdgcn_cvt_pkrtz(a0, a1);      // __fp16 ext_vector(2)
    auto hi = __builtin_amdgcn_cvt_pkrtz(a2, a3);
    f16x4 h;
    h[0] = (_Float16)lo[0]; h[1] = (_Float16)lo[1];
    h[2] = (_Float16)hi[0]; h[3] = (_Float16)hi[1];
    return h;
}

// pack f32x4 -> f16x4 (RTZ) then leaky in packed f16: max(h, 0.01h)
__device__ __forceinline__ f16x4 leaky_cvt(f32x4 a) {
    f16x4 h  = pack4(a[0], a[1], a[2], a[3]);
    f16x4 hs = h * (_Float16)0.01f;                    // v_pk_mul_f16 x2
    return __builtin_elementwise_max(h, hs);           // v_pk_max_f16 x2
}

__device__ __forceinline__ float fast_tanh(float x) {
    float e = __expf(2.0f * x);                        // v_mul + v_exp_f32
    return 1.0f - 2.0f * __builtin_amdgcn_rcpf(e + 1.0f);
}

__global__ __launch_bounds__(256, 3)
void realnvp_mfma(const float* __restrict__ x_in,
                  const char* __restrict__ wfrag,
                  float* __restrict__ out)
{
    __shared__ __align__(16) char lds[WSTRIDE];        // 44 KiB -> 3 blocks/CU

    const int tid  = threadIdx.x;
    const int w    = tid >> 6;
    const int lane = tid & 63;
    const int pl = lane & 15, g = lane >> 4;

    const int blockpx = blockIdx.x * 128;              // 128 px/block (4 waves x 32)
    const int bb   = blockpx / HWPIX;
    const int rem0 = blockpx - bb * HWPIX + w * 32;
    const float* xb = x_in + (size_t)bb * 8 * HWPIX + rem0;

    float xv[2][4];
    float logdet[2] = {0.f, 0.f};
#pragma unroll
    for (int t = 0; t < 2; ++t)
#pragma unroll
        for (int e = 0; e < 4; ++e)
            xv[t][e] = (g < 2) ? xb[(size_t)(4 * g + e) * HWPIX + t * 16 + pl] : 0.f;

#pragma unroll 1
    for (int st = 0; st < 8; ++st) {
        __syncthreads();                               // prior-stage LDS reads done
        {
            const char* gsrc = wfrag + st * WSTRIDE + tid * 16;
            char*       ldst = lds + tid * 16;
#pragma unroll
            for (int it = 0; it < 11; ++it)
                *(u32x4*)(ldst + it * 4096) = *(const u32x4*)(gsrc + it * 4096);
        }
        __syncthreads();

        // x B-fragments (f16); lanes g>=2 are don't-care (A cols k>=8 are zero)
        f16x4 xh[2];
#pragma unroll
        for (int t = 0; t < 2; ++t)
            xh[t] = pack4(xv[t][0], xv[t][1], xv[t][2], xv[t][3]);

        // ---- L1 (K=16): h1 = leaky(W1pad @ x + b1) , bias = C-init ----
        f16x4 h1[2][8];
        {
            f16x4 w1f[8];
#pragma unroll
            for (int pr = 0; pr < 4; ++pr)
                load_pair(lds + pr * 1024 + lane * 16, w1f[2 * pr], w1f[2 * pr + 1]);
#pragma unroll
            for (int m = 0; m < 8; ++m) {
                f32x4 bv = *(const f32x4*)(lds + B1OFF + m * 64 + g * 16);
#pragma unroll
                for (int t = 0; t < 2; ++t) {
                    f32x4 acc = __builtin_amdgcn_mfma_f32_16x16x16f16(w1f[m], xh[t], bv, 0, 0, 0);
                    h1[t][m] = leaky_cvt(acc);
                }
            }
        }

        // ---- L2 (K=32 x4): h2 = leaky(W2 @ h1 + b2) ----
        f16x4 h2[2][8];
#pragma unroll
        for (int m = 0; m < 8; ++m) {
            f16x8 wf[4];
#pragma unroll
            for (int c = 0; c < 4; ++c)
                wf[c] = *(const f16x8*)(lds + L2OFF + (m * 4 + c) * 1024 + lane * 16);
            f32x4 bv = *(const f32x4*)(lds + B2OFF + m * 64 + g * 16);
#pragma unroll
            for (int t = 0; t < 2; ++t) {
                f32x4 acc = bv;
#pragma unroll
                for (int c = 0; c < 4; ++c)
                    acc = __builtin_amdgcn_mfma_f32_16x16x32_f16(
                        wf[c], cat8(h1[t][2 * c], h1[t][2 * c + 1]), acc, 0, 0, 0);
                h2[t][m] = leaky_cvt(acc);
            }
        }

        // ---- L3 (K=32 x4) + coupling ----
        {
            f16x8 w3f[4];
#pragma unroll
            for (int c = 0; c < 4; ++c)
                w3f[c] = *(const f16x8*)(lds + L3OFF + c * 1024 + lane * 16);
            f32x4 bv3 = *(const f32x4*)(lds + B3OFF + g * 16);

            const int pat = st & 3;
#pragma unroll
            for (int t = 0; t < 2; ++t) {
                f32x4 acc = bv3;
#pragma unroll
                for (int c = 0; c < 4; ++c)
                    acc = __builtin_amdgcn_mfma_f32_16x16x32_f16(
                        w3f[c], cat8(h2[t][2 * c], h2[t][2 * c + 1]), acc, 0, 0, 0);

                // D rows: g0 -> st[0..3] (s-pre), g1 -> st[4..7] (t-pre)
                float sv[4], ov[4];
#pragma unroll
                for (int r = 0; r < 4; ++r) sv[r] = fast_tanh(acc[r]);
#pragma unroll
                for (int r = 0; r < 4; ++r)
                    ov[r] = __int_as_float(
                        __builtin_amdgcn_ds_swizzle(__float_as_int(sv[r]), 0x401F)); // lane^16

                if (g == 0) logdet[t] += sv[0] + sv[1] + sv[2] + sv[3];

                float xn[4];
#pragma unroll
                for (int e = 0; e < 4; ++e) xn[e] = xv[t][e];
                if (pat == 0) {            // ci={0,1,2,3} @ g0
#pragma unroll
                    for (int e = 0; e < 4; ++e)
                        if (g == 0) xn[e] = xv[t][e] * __expf(sv[e]) + ov[e];
                } else if (pat == 1) {     // ci={4,5,6,7} @ g1
#pragma unroll
                    for (int e = 0; e < 4; ++e)
                        if (g == 1) xn[e] = xv[t][e] * __expf(ov[e]) + sv[e];
                } else if (pat == 2) {     // ci={0,2,4,6}: even e
#pragma unroll
                    for (int e = 0; e < 4; e += 2) {
                        const int k0 = e >> 1, k1 = 2 + (e >> 1);
                        if (g == 0) xn[e] = xv[t][e] * __expf(sv[k0]) + ov[k0];
                        if (g == 1) xn[e] = xv[t][e] * __expf(ov[k1]) + sv[k1];
                    }
                } else {                   // ci={1,3,5,7}: odd e
#pragma unroll
                    for (int e = 1; e < 4; e += 2) {
                        const int k0 = e >> 1, k1 = 2 + (e >> 1);
                        if (g == 0) xn[e] = xv[t][e] * __expf(sv[k0]) + ov[k0];
                        if (g == 1) xn[e] = xv[t][e] * __expf(ov[k1]) + sv[k1];
                    }
                }
#pragma unroll
                for (int e = 0; e < 4; ++e) xv[t][e] = xn[e];
            }
        }
    }

    // ---- outputs: x (B,8,H,W) then log_det (B,1,H,W) ----
    float* outx = out + (size_t)bb * 8 * HWPIX + rem0;
#pragma unroll
    for (int t = 0; t < 2; ++t) {
        if (g < 2)
#pragma unroll
            for (int e = 0; e < 4; ++e)
                outx[(size_t)(4 * g + e) * HWPIX + t * 16 + pl] = xv[t][e];
        if (g == 0)
            out[(size_t)NPIX * 8 + (size_t)bb * HWPIX + rem0 + t * 16 + pl] = logdet[t];
    }
}

extern "C" void kernel_launch(void* const* d_in, const int* in_sizes, int n_in,
                              void* d_out, int out_size, void* d_ws, size_t ws_size,
                              hipStream_t stream)
{
    const float* x  = (const float*)d_in[0];
    const float* W1 = (const float*)d_in[1];
    const float* b1 = (const float*)d_in[2];
    const float* W2 = (const float*)d_in[3];
    const float* b2 = (const float*)d_in[4];
    const float* W3 = (const float*)d_in[5];
    const float* b3 = (const float*)d_in[6];
    float* out = (float*)d_out;
    char*  ws  = (char*)d_ws;

    hipLaunchKernelGGL(prep_frags, dim3(90), dim3(256), 0, stream,
                       W1, b1, W2, b2, W3, b3, ws);
    hipLaunchKernelGGL(realnvp_mfma, dim3(NPIX / 128), dim3(256), 0, stream,
                       x, ws, out);
}